// Round 6
// baseline (1304.244 us; speedup 1.0000x reference)
//
#include <hip/hip_runtime.h>
#include <hip/hip_bf16.h>

#define NN 50000
#define EE 800000
#define GG 512
#define HH 256
#define TT 32
#define LL 4
#define EPSF 1e-5f

typedef __attribute__((ext_vector_type(8))) short short8;
typedef __attribute__((ext_vector_type(4))) float float4v;

// ---------- bf16 helpers ----------
__device__ inline unsigned short f2b(float f) {  // RNE
    unsigned u = __float_as_uint(f);
    unsigned r = (u + 0x7FFFu + ((u >> 16) & 1u)) >> 16;
    return (unsigned short)r;
}
__device__ inline float4 bf4_to_f4(ushort4 u) {
    float4 f;
    f.x = __uint_as_float((unsigned)u.x << 16);
    f.y = __uint_as_float((unsigned)u.y << 16);
    f.z = __uint_as_float((unsigned)u.z << 16);
    f.w = __uint_as_float((unsigned)u.w << 16);
    return f;
}

// ---------------- degree / dinv ----------------
__global__ void k_degree(const int* __restrict__ dst, int* __restrict__ cnt, int E) {
    int e = blockIdx.x * 256 + threadIdx.x;
    if (e < E) atomicAdd(&cnt[dst[e]], 1);
}

__global__ void k_dinv(const int* __restrict__ cnt, float* __restrict__ dinv, int N) {
    int i = blockIdx.x * 256 + threadIdx.x;
    if (i < N) dinv[i] = rsqrtf((float)cnt[i] + 1.0f);
}

// ---------------- scan (3-phase, 1024/block) ----------------
__global__ void k_scan1(const int* __restrict__ cnt, int* __restrict__ incl,
                        int* __restrict__ bsum, int N) {
    __shared__ int s[1024];
    int i = blockIdx.x * 1024 + threadIdx.x;
    int v = (i < N) ? cnt[i] : 0;
    s[threadIdx.x] = v;
    __syncthreads();
    for (int off = 1; off < 1024; off <<= 1) {
        int t = (threadIdx.x >= off) ? s[threadIdx.x - off] : 0;
        __syncthreads();
        s[threadIdx.x] += t;
        __syncthreads();
    }
    if (i < N) incl[i] = s[threadIdx.x];
    if (threadIdx.x == 1023) bsum[blockIdx.x] = s[1023];
}

__global__ void k_scan2(int* __restrict__ bsum, int nb) {
    __shared__ int s[64];
    int v = (threadIdx.x < nb) ? bsum[threadIdx.x] : 0;
    s[threadIdx.x] = v;
    __syncthreads();
    for (int off = 1; off < 64; off <<= 1) {
        int t = (threadIdx.x >= off) ? s[threadIdx.x - off] : 0;
        __syncthreads();
        s[threadIdx.x] += t;
        __syncthreads();
    }
    if (threadIdx.x < nb) bsum[threadIdx.x] = s[threadIdx.x] - v;  // exclusive
}

__global__ void k_scan3(int* __restrict__ rs, const int* __restrict__ cnt,
                        const int* __restrict__ boff, int N) {
    int i = blockIdx.x * 256 + threadIdx.x;
    if (i < N) rs[i] = rs[i] + boff[i >> 10] - cnt[i];  // exclusive prefix
}

__global__ void k_scatter(const int* __restrict__ src, const int* __restrict__ dst,
                          const int* __restrict__ rs, int* __restrict__ cur,
                          int* __restrict__ csr, int E) {
    int e = blockIdx.x * 256 + threadIdx.x;
    if (e >= E) return;
    int d = dst[e];
    int p = rs[d] + atomicAdd(&cur[d], 1);
    csr[p] = src[e];
}

// ---------------- weight prep: Wt[l][n][k] bf16 ----------------
__global__ void k_wprep(const float* __restrict__ W, unsigned short* __restrict__ Wt) {
    int l = blockIdx.y;
    int n = blockIdx.x * 4 + (threadIdx.x >> 6);
    int kq = (threadIdx.x & 63) * 4;
    const float* Wl = W + (size_t)l * HH * HH;
    ushort4 o;
    o.x = f2b(Wl[(size_t)(kq + 0) * HH + n]);
    o.y = f2b(Wl[(size_t)(kq + 1) * HH + n]);
    o.z = f2b(Wl[(size_t)(kq + 2) * HH + n]);
    o.w = f2b(Wl[(size_t)(kq + 3) * HH + n]);
    *(ushort4*)(Wt + (size_t)l * HH * HH + (size_t)n * HH + kq) = o;
}

// ---------------- tiny projection: atom_proj (100x256) + tag_proj (3x256) ----------------
__global__ void k_proj(const float* __restrict__ atom_emb, const float* __restrict__ tag_emb,
                       const float* __restrict__ Wp, const float* __restrict__ bp,
                       float* __restrict__ aref, float* __restrict__ tref) {
    int r = blockIdx.x;
    int j = threadIdx.x;  // 256
    if (r < 100) {
        float acc = bp[j];
        for (int k = 0; k < HH; ++k) acc += atom_emb[r * HH + k] * Wp[(size_t)k * HH + j];
        aref[r * HH + j] = acc;
    } else {
        int tr = r - 100;
        float acc = 0.f;
        for (int k = 0; k < TT; ++k) acc += tag_emb[tr * TT + k] * Wp[(size_t)(HH + k) * HH + j];
        tref[tr * HH + j] = acc;
    }
}

__global__ void k_h0(const int* __restrict__ x, const int* __restrict__ tags,
                     const float* __restrict__ aref, const float* __restrict__ tref,
                     unsigned short* __restrict__ hb, int N) {
    int n = blockIdx.x;
    int lane = threadIdx.x;  // 64
    float4 a = ((const float4*)(aref + (size_t)x[n] * HH))[lane];
    float4 t = ((const float4*)(tref + (size_t)tags[n] * HH))[lane];
    ushort4 u;
    u.x = f2b(a.x + t.x); u.y = f2b(a.y + t.y);
    u.z = f2b(a.z + t.z); u.w = f2b(a.w + t.w);
    ((ushort4*)(hb + (size_t)n * HH))[lane] = u;
}

// ---------------- MFMA bf16 GEMM: hwc[8][Mpad][32] = bf16( (hb @ Wt^T) * dinv[row] ) ----------------
// Output in chunk-major layout: col n -> chunk n>>5, within n&31. 64 B rows per chunk.
__global__ __launch_bounds__(256) void k_gemm(const unsigned short* __restrict__ hb,
                                              const unsigned short* __restrict__ Wt,
                                              const float* __restrict__ dinv,
                                              unsigned short* __restrict__ hwc,
                                              int M, int Mpad) {
    __shared__ unsigned short As[128][72];
    __shared__ unsigned short Bs[128][72];
    int t = threadIdx.x;
    int lane = t & 63, w = t >> 6;
    int wr = w >> 1, wc = w & 1;
    int l15 = lane & 15, l4 = lane >> 4;
    int row0 = blockIdx.y * 128, col0 = blockIdx.x * 128;
    float4v acc[4][4];
#pragma unroll
    for (int i = 0; i < 4; ++i)
#pragma unroll
        for (int j = 0; j < 4; ++j) acc[i][j] = (float4v)0.f;

    for (int k0 = 0; k0 < 256; k0 += 64) {
        if (k0) __syncthreads();
#pragma unroll
        for (int u = 0; u < 4; ++u) {
            int idx = u * 256 + t;          // 0..1023
            int r = idx >> 3;               // 0..127
            int c = (idx & 7) * 8;          // bf16 col
            *(uint4*)&As[r][c] = *(const uint4*)(hb + (size_t)(row0 + r) * 256 + k0 + c);
            *(uint4*)&Bs[r][c] = *(const uint4*)(Wt + (size_t)(col0 + r) * 256 + k0 + c);
        }
        __syncthreads();
#pragma unroll
        for (int kk = 0; kk < 64; kk += 32) {
            short8 a[4], b[4];
#pragma unroll
            for (int i = 0; i < 4; ++i)
                a[i] = *(const short8*)&As[wr * 64 + i * 16 + l15][kk + l4 * 8];
#pragma unroll
            for (int i = 0; i < 4; ++i)
                b[i] = *(const short8*)&Bs[wc * 64 + i * 16 + l15][kk + l4 * 8];
#pragma unroll
            for (int mi = 0; mi < 4; ++mi)
#pragma unroll
                for (int ni = 0; ni < 4; ++ni)
                    acc[mi][ni] = __builtin_amdgcn_mfma_f32_16x16x32_bf16(
                        a[mi], b[ni], acc[mi][ni], 0, 0, 0);
        }
    }
    // epilogue: C/D layout col=lane&15, row=(lane>>4)*4+reg; store chunk-major
#pragma unroll
    for (int mi = 0; mi < 4; ++mi) {
        int mb = row0 + wr * 64 + mi * 16 + l4 * 4;
        float dv[4];
#pragma unroll
        for (int r = 0; r < 4; ++r) dv[r] = (mb + r < M) ? dinv[mb + r] : 0.f;
#pragma unroll
        for (int ni = 0; ni < 4; ++ni) {
            int n = col0 + wc * 64 + ni * 16 + l15;
            int ch = n >> 5, wi = n & 31;
            unsigned short* obase = hwc + (size_t)ch * Mpad * 32 + wi;
#pragma unroll
            for (int r = 0; r < 4; ++r) {
                if (mb + r < M)
                    obase[(size_t)(mb + r) * 32] = f2b(acc[mi][ni][r] * dv[r]);
            }
        }
    }
}

// ---------------- chunked CSR aggregation: one wave per node per chunk ----------------
// hwc[8][Mpad][32] bf16 (64 B rows) -> per-chunk working set 3.2 MB, fits XCD L2.
// Wave: 4 quarter-waves each gather one row (16 lanes x ushort2 = 64 B).
// Work list: item 0 = self row n (hwc already carries dinv factor), items 1..deg = csr.
__global__ __launch_bounds__(256) void k_agg(const unsigned short* __restrict__ hwc,
                      unsigned short* __restrict__ aggb,
                      const int* __restrict__ csr, const int* __restrict__ rs,
                      const int* __restrict__ cnt, const float* __restrict__ dinv,
                      const float* __restrict__ bias, int N, int Mpad) {
    int wave = threadIdx.x >> 6;
    int lane = threadIdx.x & 63;
    int n = blockIdx.x * 4 + wave;
    if (n >= N) return;
    int c = blockIdx.y;   // chunk 0..7  (x-major dispatch groups chunks in time)
    const unsigned short* base = hwc + (size_t)c * Mpad * 32;
    int q = lane >> 4;        // quarter 0..3
    int colp = lane & 15;     // column pair; col = colp*2
    float dn = dinv[n];
    int start = rs[n] - 1;    // item i (>=1) -> csr[start + i]
    int len = cnt[n] + 1;
    float accx = 0.f, accy = 0.f;
    int i = 0;
    for (; i + 16 <= len; i += 16) {
        int i0 = i + q;
        int r0 = (i0 == 0) ? n : csr[start + i0];
        int r1 = csr[start + i0 + 4];
        int r2 = csr[start + i0 + 8];
        int r3 = csr[start + i0 + 12];
        unsigned v0 = *(const unsigned*)(base + (size_t)r0 * 32 + colp * 2);
        unsigned v1 = *(const unsigned*)(base + (size_t)r1 * 32 + colp * 2);
        unsigned v2 = *(const unsigned*)(base + (size_t)r2 * 32 + colp * 2);
        unsigned v3 = *(const unsigned*)(base + (size_t)r3 * 32 + colp * 2);
        accx += (__uint_as_float(v0 << 16) + __uint_as_float(v1 << 16))
              + (__uint_as_float(v2 << 16) + __uint_as_float(v3 << 16));
        accy += (__uint_as_float(v0 & 0xFFFF0000u) + __uint_as_float(v1 & 0xFFFF0000u))
              + (__uint_as_float(v2 & 0xFFFF0000u) + __uint_as_float(v3 & 0xFFFF0000u));
    }
    for (; i < len; i += 4) {
        int item = i + q;
        if (item < len) {
            int row = (item == 0) ? n : csr[start + item];
            unsigned v = *(const unsigned*)(base + (size_t)row * 32 + colp * 2);
            accx += __uint_as_float(v << 16);
            accy += __uint_as_float(v & 0xFFFF0000u);
        }
    }
    accx += __shfl_xor(accx, 16);
    accy += __shfl_xor(accy, 16);
    accx += __shfl_xor(accx, 32);
    accy += __shfl_xor(accy, 32);
    if (q == 0) {
        int col = c * 32 + colp * 2;
        unsigned short ux = f2b(accx * dn + bias[col]);
        unsigned short uy = f2b(accy * dn + bias[col + 1]);
        *(unsigned*)(aggb + (size_t)n * 256 + col) = (unsigned)ux | ((unsigned)uy << 16);
    }
}

// ---------------- BN stats (col sum / sumsq) over bf16 agg ----------------
__global__ __launch_bounds__(256) void k_bnstats(const ushort4* __restrict__ aggb,
                                                 float* __restrict__ colsum,
                                                 float* __restrict__ colsq, int N) {
    __shared__ float4 ssum[4][64];
    __shared__ float4 ssq[4][64];
    int lane = threadIdx.x & 63;
    int wv = threadIdx.x >> 6;
    int rows_per = (N + gridDim.x - 1) / gridDim.x;
    int r0 = blockIdx.x * rows_per;
    int r1 = r0 + rows_per; if (r1 > N) r1 = N;
    float4 s = make_float4(0.f, 0.f, 0.f, 0.f);
    float4 s2 = make_float4(0.f, 0.f, 0.f, 0.f);
    for (int r = r0 + wv; r < r1; r += 4) {
        float4 v = bf4_to_f4(aggb[(size_t)r * 64 + lane]);
        s.x += v.x; s.y += v.y; s.z += v.z; s.w += v.w;
        s2.x += v.x * v.x; s2.y += v.y * v.y; s2.z += v.z * v.z; s2.w += v.w * v.w;
    }
    ssum[wv][lane] = s;
    ssq[wv][lane] = s2;
    __syncthreads();
    int j = lane * 4;
    if (wv == 0) {
        float4 a = ssum[0][lane], b = ssum[1][lane], c = ssum[2][lane], d = ssum[3][lane];
        atomicAdd(&colsum[j + 0], a.x + b.x + c.x + d.x);
        atomicAdd(&colsum[j + 1], a.y + b.y + c.y + d.y);
        atomicAdd(&colsum[j + 2], a.z + b.z + c.z + d.z);
        atomicAdd(&colsum[j + 3], a.w + b.w + c.w + d.w);
    } else if (wv == 1) {
        float4 a = ssq[0][lane], b = ssq[1][lane], c = ssq[2][lane], d = ssq[3][lane];
        atomicAdd(&colsq[j + 0], a.x + b.x + c.x + d.x);
        atomicAdd(&colsq[j + 1], a.y + b.y + c.y + d.y);
        atomicAdd(&colsq[j + 2], a.z + b.z + c.z + d.z);
        atomicAdd(&colsq[j + 3], a.w + b.w + c.w + d.w);
    }
}

// ---------------- BN + ReLU + residual (bf16 agg in, bf16 state in hb) ----------------
__global__ void k_epi(const ushort4* __restrict__ aggb, ushort4* __restrict__ hb,
                      const float4* __restrict__ colsum, const float4* __restrict__ colsq,
                      const float4* __restrict__ g4, const float4* __restrict__ b4,
                      int total, float invN) {
    int idx = blockIdx.x * 256 + threadIdx.x;
    if (idx >= total) return;
    int q = idx & 63;
    float4 a = bf4_to_f4(aggb[idx]);
    float4 s = colsum[q], s2 = colsq[q], g = g4[q], b = b4[q];
    float4 hv = bf4_to_f4(hb[idx]);
    float mu, var, v;
    mu = s.x * invN; var = s2.x * invN - mu * mu;
    v = (a.x - mu) * rsqrtf(var + EPSF) * g.x + b.x; hv.x += fmaxf(v, 0.f);
    mu = s.y * invN; var = s2.y * invN - mu * mu;
    v = (a.y - mu) * rsqrtf(var + EPSF) * g.y + b.y; hv.y += fmaxf(v, 0.f);
    mu = s.z * invN; var = s2.z * invN - mu * mu;
    v = (a.z - mu) * rsqrtf(var + EPSF) * g.z + b.z; hv.z += fmaxf(v, 0.f);
    mu = s.w * invN; var = s2.w * invN - mu * mu;
    v = (a.w - mu) * rsqrtf(var + EPSF) * g.w + b.w; hv.w += fmaxf(v, 0.f);
    ushort4 u;
    u.x = f2b(hv.x); u.y = f2b(hv.y); u.z = f2b(hv.z); u.w = f2b(hv.w);
    hb[idx] = u;
}

// ---------------- graph boundaries (batch is sorted) ----------------
__global__ void k_ginit(int* __restrict__ gstart, int G, int N) {
    int g = blockIdx.x * 256 + threadIdx.x;
    if (g <= G) gstart[g] = N;
}

__global__ void k_gbound(const int* __restrict__ batch, int* __restrict__ gstart, int N) {
    int n = blockIdx.x * 256 + threadIdx.x;
    if (n >= N) return;
    int b = batch[n];
    int prev = (n == 0) ? -1 : batch[n - 1];
    for (int g = prev + 1; g <= b; ++g) gstart[g] = n;
}

// ---------------- segmented mean pool (bf16 in): one block (4 waves) per graph ----------------
__global__ void k_pool(const unsigned short* __restrict__ hb, const int* __restrict__ gstart,
                       float* __restrict__ pooled) {
    __shared__ float4 sm[4][64];
    int g = blockIdx.x;
    int t = threadIdx.x;
    int lane = t & 63, wv = t >> 6;
    int s = gstart[g], e = gstart[g + 1];
    float4 acc = make_float4(0.f, 0.f, 0.f, 0.f);
    for (int n = s + wv; n < e; n += 4) {
        float4 v = bf4_to_f4(((const ushort4*)(hb + (size_t)n * HH))[lane]);
        acc.x += v.x; acc.y += v.y; acc.z += v.z; acc.w += v.w;
    }
    sm[wv][lane] = acc;
    __syncthreads();
    if (wv == 0) {
        float4 a = sm[0][lane], b = sm[1][lane], c = sm[2][lane], d = sm[3][lane];
        float inv = 1.0f / fmaxf((float)(e - s), 1.0f);
        float4 r;
        r.x = (a.x + b.x + c.x + d.x) * inv;
        r.y = (a.y + b.y + c.y + d.y) * inv;
        r.z = (a.z + b.z + c.z + d.z) * inv;
        r.w = (a.w + b.w + c.w + d.w) * inv;
        ((float4*)pooled)[(size_t)g * 64 + lane] = r;
    }
}

// ---------------- MLP head: one block per graph ----------------
__global__ void k_head(const float* __restrict__ pooled,
                       const float* __restrict__ W1, const float* __restrict__ b1,
                       const float* __restrict__ W2, const float* __restrict__ b2,
                       float* __restrict__ out) {
    __shared__ float prow[256];
    __shared__ float hred[128];
    int g = blockIdx.x, t = threadIdx.x;  // 128 threads
    prow[t] = pooled[(size_t)g * HH + t];
    prow[t + 128] = pooled[(size_t)g * HH + t + 128];
    __syncthreads();
    float acc = b1[t];
    for (int k = 0; k < HH; ++k) acc += prow[k] * W1[(size_t)k * 128 + t];
    float hid = fmaxf(acc, 0.f);
    hred[t] = hid * W2[t];
    __syncthreads();
    for (int off = 64; off > 0; off >>= 1) {
        if (t < off) hred[t] += hred[t + off];
        __syncthreads();
    }
    if (t == 0) out[g] = hred[0] + b2[0];
}

extern "C" void kernel_launch(void* const* d_in, const int* in_sizes, int n_in,
                              void* d_out, int out_size, void* d_ws, size_t ws_size,
                              hipStream_t stream) {
    const int* x        = (const int*)d_in[0];
    const int* tags     = (const int*)d_in[1];
    const int* ei       = (const int*)d_in[2];
    const int* batch    = (const int*)d_in[3];
    const float* atom_e = (const float*)d_in[4];
    const float* tag_e  = (const float*)d_in[5];
    const float* Wp     = (const float*)d_in[6];
    const float* bp     = (const float*)d_in[7];
    const float* gcn_W  = (const float*)d_in[8];
    const float* gcn_b  = (const float*)d_in[9];
    const float* bn_g   = (const float*)d_in[10];
    const float* bn_b   = (const float*)d_in[11];
    const float* W1     = (const float*)d_in[12];
    const float* b1     = (const float*)d_in[13];
    const float* W2     = (const float*)d_in[14];
    const float* b2     = (const float*)d_in[15];
    float* out = (float*)d_out;

    const int N = NN, E = EE, G = GG, H = HH;
    const int Mpad = ((N + 127) / 128) * 128;  // 50048

    char* p = (char*)d_ws;
    auto alloc = [&](size_t bytes) {
        void* r = (void*)p;
        p += (bytes + 255) & ~(size_t)255;
        return r;
    };
    unsigned short* hb  = (unsigned short*)alloc((size_t)Mpad * H * 2);
    unsigned short* hwc = (unsigned short*)alloc((size_t)Mpad * H * 2);  // [8][Mpad][32]
    unsigned short* Wt  = (unsigned short*)alloc((size_t)LL * H * H * 2);
    unsigned short* aggb= (unsigned short*)alloc((size_t)N * H * 2);
    float* dinv = (float*)alloc((size_t)N * 4);
    int* cnt    = (int*)alloc((size_t)N * 4);
    int* rs     = (int*)alloc((size_t)N * 4);
    int* cur    = (int*)alloc((size_t)N * 4);
    int* csr    = (int*)alloc((size_t)E * 4);
    int* bsum   = (int*)alloc(64 * 4);
    float* aref = (float*)alloc(100 * (size_t)H * 4);
    float* tref = (float*)alloc(3 * (size_t)H * 4);
    float* cstat= (float*)alloc(2 * (size_t)H * 4);  // colsum | colsq
    int* gstart = (int*)alloc((size_t)(G + 1) * 4);
    float* pooled = (float*)alloc((size_t)G * H * 4);

    const int* src = ei;
    const int* dst = ei + E;

    hipMemsetAsync(cnt, 0, (size_t)N * 4, stream);
    hipMemsetAsync(cur, 0, (size_t)N * 4, stream);

    k_degree<<<(E + 255) / 256, 256, 0, stream>>>(dst, cnt, E);
    k_dinv<<<(N + 255) / 256, 256, 0, stream>>>(cnt, dinv, N);

    int nb = (N + 1023) / 1024;
    k_scan1<<<nb, 1024, 0, stream>>>(cnt, rs, bsum, N);
    k_scan2<<<1, 64, 0, stream>>>(bsum, nb);
    k_scan3<<<(N + 255) / 256, 256, 0, stream>>>(rs, cnt, bsum, N);
    k_scatter<<<(E + 255) / 256, 256, 0, stream>>>(src, dst, rs, cur, csr, E);

    k_ginit<<<(G + 256) / 256, 256, 0, stream>>>(gstart, G, N);
    k_gbound<<<(N + 255) / 256, 256, 0, stream>>>(batch, gstart, N);

    k_wprep<<<dim3(64, LL), 256, 0, stream>>>(gcn_W, Wt);
    k_proj<<<103, 256, 0, stream>>>(atom_e, tag_e, Wp, bp, aref, tref);
    k_h0<<<N, 64, 0, stream>>>(x, tags, aref, tref, hb, N);

    for (int l = 0; l < LL; ++l) {
        k_gemm<<<dim3(2, Mpad / 128), 256, 0, stream>>>(
            hb, Wt + (size_t)l * H * H, dinv, hwc, N, Mpad);
        k_agg<<<dim3((N + 3) / 4, 8), 256, 0, stream>>>(hwc, aggb, csr, rs, cnt, dinv,
                                                        gcn_b + (size_t)l * H, N, Mpad);
        hipMemsetAsync(cstat, 0, 2 * (size_t)H * 4, stream);
        k_bnstats<<<512, 256, 0, stream>>>((const ushort4*)aggb, cstat, cstat + H, N);
        k_epi<<<(N * 64 + 255) / 256, 256, 0, stream>>>(
            (const ushort4*)aggb, (ushort4*)hb,
            (const float4*)cstat, (const float4*)(cstat + H),
            (const float4*)(bn_g + (size_t)l * H), (const float4*)(bn_b + (size_t)l * H),
            N * 64, 1.0f / (float)N);
    }

    k_pool<<<G, 256, 0, stream>>>(hb, gstart, pooled);
    k_head<<<G, 128, 0, stream>>>(pooled, W1, b1, W2, b2, out);
}

// Round 7
// 866.838 us; speedup vs baseline: 1.5046x; 1.5046x over previous
//
#include <hip/hip_runtime.h>
#include <hip/hip_bf16.h>

#define NN 50000
#define EE 800000
#define GG 512
#define HH 256
#define TT 32
#define LL 4
#define EPSF 1e-5f

typedef __attribute__((ext_vector_type(8))) short short8;
typedef __attribute__((ext_vector_type(4))) float float4v;

// ---------- bf16 helpers ----------
__device__ inline unsigned short f2b(float f) {  // RNE
    unsigned u = __float_as_uint(f);
    unsigned r = (u + 0x7FFFu + ((u >> 16) & 1u)) >> 16;
    return (unsigned short)r;
}
__device__ inline unsigned pack2(float lo, float hi) {
    return (unsigned)f2b(lo) | ((unsigned)f2b(hi) << 16);
}
__device__ inline float4 bf4_to_f4(ushort4 u) {
    float4 f;
    f.x = __uint_as_float((unsigned)u.x << 16);
    f.y = __uint_as_float((unsigned)u.y << 16);
    f.z = __uint_as_float((unsigned)u.z << 16);
    f.w = __uint_as_float((unsigned)u.w << 16);
    return f;
}

// ---------------- degree ----------------
__global__ void k_degree(const int* __restrict__ dst, int* __restrict__ cnt, int E) {
    int e = blockIdx.x * 256 + threadIdx.x;
    if (e < E) atomicAdd(&cnt[dst[e]], 1);
}

// ---------------- scan (3-phase) ----------------
__global__ void k_scan1(const int* __restrict__ cnt, int* __restrict__ incl,
                        int* __restrict__ bsum, int N) {
    __shared__ int s[1024];
    int i = blockIdx.x * 1024 + threadIdx.x;
    int v = (i < N) ? cnt[i] : 0;
    s[threadIdx.x] = v;
    __syncthreads();
    for (int off = 1; off < 1024; off <<= 1) {
        int t = (threadIdx.x >= off) ? s[threadIdx.x - off] : 0;
        __syncthreads();
        s[threadIdx.x] += t;
        __syncthreads();
    }
    if (i < N) incl[i] = s[threadIdx.x];
    if (threadIdx.x == 1023) bsum[blockIdx.x] = s[1023];
}

__global__ void k_scan2(int* __restrict__ bsum, int nb) {
    __shared__ int s[64];
    int v = (threadIdx.x < nb) ? bsum[threadIdx.x] : 0;
    s[threadIdx.x] = v;
    __syncthreads();
    for (int off = 1; off < 64; off <<= 1) {
        int t = (threadIdx.x >= off) ? s[threadIdx.x - off] : 0;
        __syncthreads();
        s[threadIdx.x] += t;
        __syncthreads();
    }
    if (threadIdx.x < nb) bsum[threadIdx.x] = s[threadIdx.x] - v;  // exclusive
}

// scan3 + dinv fused
__global__ void k_scan3(int* __restrict__ rs, const int* __restrict__ cnt,
                        const int* __restrict__ boff, float* __restrict__ dinv, int N) {
    int i = blockIdx.x * 256 + threadIdx.x;
    if (i < N) {
        int c = cnt[i];
        rs[i] = rs[i] + boff[i >> 10] - c;  // exclusive prefix
        dinv[i] = rsqrtf((float)c + 1.0f);
    }
}

__global__ void k_scatter(const int* __restrict__ src, const int* __restrict__ dst,
                          const int* __restrict__ rs, int* __restrict__ cur,
                          int* __restrict__ csr, int E) {
    int e = blockIdx.x * 256 + threadIdx.x;
    if (e >= E) return;
    int d = dst[e];
    int p = rs[d] + atomicAdd(&cur[d], 1);
    csr[p] = src[e];
}

// ---------------- graph boundaries (batch sorted), tail handled inline ----------------
__global__ void k_gbound(const int* __restrict__ batch, int* __restrict__ gstart,
                         int N, int G) {
    int n = blockIdx.x * 256 + threadIdx.x;
    if (n >= N) return;
    int b = batch[n];
    int prev = (n == 0) ? -1 : batch[n - 1];
    for (int g = prev + 1; g <= b; ++g) gstart[g] = n;
    if (n == N - 1)
        for (int g = b + 1; g <= G; ++g) gstart[g] = N;
}

// ---------------- fused proj (atom/tag tables) + weight transpose ----------------
__global__ void k_projw(const float* __restrict__ atom_emb, const float* __restrict__ tag_emb,
                        const float* __restrict__ Wp, const float* __restrict__ bp,
                        const float* __restrict__ W,
                        float* __restrict__ aref, float* __restrict__ tref,
                        unsigned short* __restrict__ Wt) {
    int blk = blockIdx.x;
    if (blk < 256) {  // wprep: Wt[l][n][k] bf16
        int l = blk >> 6;
        int bx = blk & 63;
        int n = bx * 4 + (threadIdx.x >> 6);
        int kq = (threadIdx.x & 63) * 4;
        const float* Wl = W + (size_t)l * HH * HH;
        ushort4 o;
        o.x = f2b(Wl[(size_t)(kq + 0) * HH + n]);
        o.y = f2b(Wl[(size_t)(kq + 1) * HH + n]);
        o.z = f2b(Wl[(size_t)(kq + 2) * HH + n]);
        o.w = f2b(Wl[(size_t)(kq + 3) * HH + n]);
        *(ushort4*)(Wt + (size_t)l * HH * HH + (size_t)n * HH + kq) = o;
    } else {
        int r = blk - 256;  // 0..102
        int j = threadIdx.x;
        if (r < 100) {
            float acc = bp[j];
            for (int k = 0; k < HH; ++k) acc += atom_emb[r * HH + k] * Wp[(size_t)k * HH + j];
            aref[r * HH + j] = acc;
        } else {
            int tr = r - 100;
            float acc = 0.f;
            for (int k = 0; k < TT; ++k) acc += tag_emb[tr * TT + k] * Wp[(size_t)(HH + k) * HH + j];
            tref[tr * HH + j] = acc;
        }
    }
}

// ---------------- fused MFMA GEMM ----------------
// hwb[M,256] = bf16( (A @ Wt^T) * dinv[row] )
// mode 0 (layer 0): A[row] = aref[x[row]] + tref[tags[row]]        (h0 fused)
// mode 1 (layers 1+): A[row] = hb_read[row] + relu(bn(aggb[row]))  (epi fused)
// blockIdx.x==0 additionally writes A (the new residual state) to hb_out.
__global__ __launch_bounds__(256) void k_gemm(
    const unsigned short* __restrict__ hb_read,
    const unsigned short* __restrict__ Wt,
    const float* __restrict__ dinv,
    unsigned short* __restrict__ hwb,
    int mode,
    const int* __restrict__ x, const int* __restrict__ tags,
    const float* __restrict__ aref, const float* __restrict__ tref,
    const unsigned short* __restrict__ aggb,
    const float* __restrict__ colsum, const float* __restrict__ colsq,
    const float* __restrict__ bng, const float* __restrict__ bnb,
    unsigned short* __restrict__ hb_out,
    int M, float invN) {
    __shared__ unsigned short As[128][72];
    __shared__ unsigned short Bs[128][72];
    __shared__ float sc[256], sh[256];
    int t = threadIdx.x;
    int lane = t & 63, w = t >> 6;
    int wr = w >> 1, wc = w & 1;
    int l15 = lane & 15, l4 = lane >> 4;
    int row0 = blockIdx.y * 128, col0 = blockIdx.x * 128;
    bool wantWrite = (blockIdx.x == 0);

    if (mode == 1) {  // per-column BN scale/shift
        float mu = colsum[t] * invN;
        float var = colsq[t] * invN - mu * mu;
        float s = bng[t] * rsqrtf(var + EPSF);
        sc[t] = s;
        sh[t] = bnb[t] - mu * s;
    }
    __syncthreads();

    float4v acc[4][4];
#pragma unroll
    for (int i = 0; i < 4; ++i)
#pragma unroll
        for (int j = 0; j < 4; ++j) acc[i][j] = (float4v)0.f;

    for (int k0 = 0; k0 < 256; k0 += 64) {
        if (k0) __syncthreads();
#pragma unroll
        for (int u = 0; u < 4; ++u) {
            int idx = u * 256 + t;          // 0..1023
            int r = idx >> 3;               // 0..127
            int c = (idx & 7) * 8;          // bf16 col within 64-seg
            int grow = row0 + r;
            int gcol = k0 + c;              // global feature col
            // B tile
            *(uint4*)&Bs[r][c] = *(const uint4*)(Wt + (size_t)(col0 + r) * 256 + gcol);
            // A tile (computed)
            uint4 ov;
            if (grow < M) {
                unsigned o[4];
                if (mode == 0) {
                    const float* ar = aref + (size_t)x[grow] * 256 + gcol;
                    const float* tr = tref + (size_t)tags[grow] * 256 + gcol;
                    float4 a0 = *(const float4*)ar, a1 = *(const float4*)(ar + 4);
                    float4 t0 = *(const float4*)tr, t1 = *(const float4*)(tr + 4);
                    o[0] = pack2(a0.x + t0.x, a0.y + t0.y);
                    o[1] = pack2(a0.z + t0.z, a0.w + t0.w);
                    o[2] = pack2(a1.x + t1.x, a1.y + t1.y);
                    o[3] = pack2(a1.z + t1.z, a1.w + t1.w);
                } else {
                    uint4 hv = *(const uint4*)(hb_read + (size_t)grow * 256 + gcol);
                    uint4 av = *(const uint4*)(aggb + (size_t)grow * 256 + gcol);
                    const unsigned* hvp = (const unsigned*)&hv;
                    const unsigned* avp = (const unsigned*)&av;
#pragma unroll
                    for (int j = 0; j < 4; ++j) {
                        unsigned hj = hvp[j], aj = avp[j];
                        float h0 = __uint_as_float(hj << 16);
                        float h1 = __uint_as_float(hj & 0xFFFF0000u);
                        float a0 = __uint_as_float(aj << 16);
                        float a1 = __uint_as_float(aj & 0xFFFF0000u);
                        int cc = gcol + j * 2;
                        float v0 = fmaxf(a0 * sc[cc] + sh[cc], 0.f);
                        float v1 = fmaxf(a1 * sc[cc + 1] + sh[cc + 1], 0.f);
                        o[j] = pack2(h0 + v0, h1 + v1);
                    }
                }
                ov = make_uint4(o[0], o[1], o[2], o[3]);
                if (wantWrite) *(uint4*)(hb_out + (size_t)grow * 256 + gcol) = ov;
            } else {
                ov = make_uint4(0u, 0u, 0u, 0u);
            }
            *(uint4*)&As[r][c] = ov;
        }
        __syncthreads();
#pragma unroll
        for (int kk = 0; kk < 64; kk += 32) {
            short8 a[4], b[4];
#pragma unroll
            for (int i = 0; i < 4; ++i)
                a[i] = *(const short8*)&As[wr * 64 + i * 16 + l15][kk + l4 * 8];
#pragma unroll
            for (int i = 0; i < 4; ++i)
                b[i] = *(const short8*)&Bs[wc * 64 + i * 16 + l15][kk + l4 * 8];
#pragma unroll
            for (int mi = 0; mi < 4; ++mi)
#pragma unroll
                for (int ni = 0; ni < 4; ++ni)
                    acc[mi][ni] = __builtin_amdgcn_mfma_f32_16x16x32_bf16(
                        a[mi], b[ni], acc[mi][ni], 0, 0, 0);
        }
    }
    // epilogue: C/D layout col=lane&15, row=(lane>>4)*4+reg
#pragma unroll
    for (int mi = 0; mi < 4; ++mi) {
        int mb = row0 + wr * 64 + mi * 16 + l4 * 4;
        float dv[4];
#pragma unroll
        for (int r = 0; r < 4; ++r) dv[r] = (mb + r < M) ? dinv[mb + r] : 0.f;
#pragma unroll
        for (int ni = 0; ni < 4; ++ni) {
            int n = col0 + wc * 64 + ni * 16 + l15;
#pragma unroll
            for (int r = 0; r < 4; ++r) {
                if (mb + r < M)
                    hwb[(size_t)(mb + r) * 256 + n] = f2b(acc[mi][ni][r] * dv[r]);
            }
        }
    }
}

// ---------------- CSR aggregation (bf16 row gathers, 8x unrolled): one wave/node ----------------
__global__ void k_agg(const unsigned short* __restrict__ hwb, unsigned short* __restrict__ aggb,
                      const int* __restrict__ csr, const int* __restrict__ rs,
                      const int* __restrict__ cnt, const float* __restrict__ dinv,
                      const float* __restrict__ bias, int N) {
    int wave = threadIdx.x >> 6;
    int lane = threadIdx.x & 63;
    int n = blockIdx.x * 4 + wave;
    if (n >= N) return;
    float dn = dinv[n];
    int e = rs[n];
    int end = e + cnt[n];
    // self term (hwb already carries dinv[src])
    float4 acc = bf4_to_f4(((const ushort4*)(hwb + (size_t)n * HH))[lane]);
    for (; e + 8 <= end; e += 8) {
        int s0 = csr[e],     s1 = csr[e + 1], s2 = csr[e + 2], s3 = csr[e + 3];
        int s4 = csr[e + 4], s5 = csr[e + 5], s6 = csr[e + 6], s7 = csr[e + 7];
        float4 m0 = bf4_to_f4(((const ushort4*)(hwb + (size_t)s0 * HH))[lane]);
        float4 m1 = bf4_to_f4(((const ushort4*)(hwb + (size_t)s1 * HH))[lane]);
        float4 m2 = bf4_to_f4(((const ushort4*)(hwb + (size_t)s2 * HH))[lane]);
        float4 m3 = bf4_to_f4(((const ushort4*)(hwb + (size_t)s3 * HH))[lane]);
        float4 m4 = bf4_to_f4(((const ushort4*)(hwb + (size_t)s4 * HH))[lane]);
        float4 m5 = bf4_to_f4(((const ushort4*)(hwb + (size_t)s5 * HH))[lane]);
        float4 m6 = bf4_to_f4(((const ushort4*)(hwb + (size_t)s6 * HH))[lane]);
        float4 m7 = bf4_to_f4(((const ushort4*)(hwb + (size_t)s7 * HH))[lane]);
        acc.x += ((m0.x + m1.x) + (m2.x + m3.x)) + ((m4.x + m5.x) + (m6.x + m7.x));
        acc.y += ((m0.y + m1.y) + (m2.y + m3.y)) + ((m4.y + m5.y) + (m6.y + m7.y));
        acc.z += ((m0.z + m1.z) + (m2.z + m3.z)) + ((m4.z + m5.z) + (m6.z + m7.z));
        acc.w += ((m0.w + m1.w) + (m2.w + m3.w)) + ((m4.w + m5.w) + (m6.w + m7.w));
    }
    for (; e + 4 <= end; e += 4) {
        int s0 = csr[e], s1 = csr[e + 1], s2 = csr[e + 2], s3 = csr[e + 3];
        float4 m0 = bf4_to_f4(((const ushort4*)(hwb + (size_t)s0 * HH))[lane]);
        float4 m1 = bf4_to_f4(((const ushort4*)(hwb + (size_t)s1 * HH))[lane]);
        float4 m2 = bf4_to_f4(((const ushort4*)(hwb + (size_t)s2 * HH))[lane]);
        float4 m3 = bf4_to_f4(((const ushort4*)(hwb + (size_t)s3 * HH))[lane]);
        acc.x += (m0.x + m1.x) + (m2.x + m3.x);
        acc.y += (m0.y + m1.y) + (m2.y + m3.y);
        acc.z += (m0.z + m1.z) + (m2.z + m3.z);
        acc.w += (m0.w + m1.w) + (m2.w + m3.w);
    }
    for (; e < end; ++e) {
        int s = csr[e];
        float4 m = bf4_to_f4(((const ushort4*)(hwb + (size_t)s * HH))[lane]);
        acc.x += m.x; acc.y += m.y; acc.z += m.z; acc.w += m.w;
    }
    float4 b = ((const float4*)bias)[lane];
    ushort4 u;
    u.x = f2b(acc.x * dn + b.x); u.y = f2b(acc.y * dn + b.y);
    u.z = f2b(acc.z * dn + b.z); u.w = f2b(acc.w * dn + b.w);
    ((ushort4*)(aggb + (size_t)n * HH))[lane] = u;
}

// ---------------- BN stats (col sum / sumsq) over bf16 agg ----------------
__global__ __launch_bounds__(256) void k_bnstats(const ushort4* __restrict__ aggb,
                                                 float* __restrict__ colsum,
                                                 float* __restrict__ colsq, int N) {
    __shared__ float4 ssum[4][64];
    __shared__ float4 ssq[4][64];
    int lane = threadIdx.x & 63;
    int wv = threadIdx.x >> 6;
    int rows_per = (N + gridDim.x - 1) / gridDim.x;
    int r0 = blockIdx.x * rows_per;
    int r1 = r0 + rows_per; if (r1 > N) r1 = N;
    float4 s = make_float4(0.f, 0.f, 0.f, 0.f);
    float4 s2 = make_float4(0.f, 0.f, 0.f, 0.f);
    for (int r = r0 + wv; r < r1; r += 4) {
        float4 v = bf4_to_f4(aggb[(size_t)r * 64 + lane]);
        s.x += v.x; s.y += v.y; s.z += v.z; s.w += v.w;
        s2.x += v.x * v.x; s2.y += v.y * v.y; s2.z += v.z * v.z; s2.w += v.w * v.w;
    }
    ssum[wv][lane] = s;
    ssq[wv][lane] = s2;
    __syncthreads();
    int j = lane * 4;
    if (wv == 0) {
        float4 a = ssum[0][lane], b = ssum[1][lane], c = ssum[2][lane], d = ssum[3][lane];
        atomicAdd(&colsum[j + 0], a.x + b.x + c.x + d.x);
        atomicAdd(&colsum[j + 1], a.y + b.y + c.y + d.y);
        atomicAdd(&colsum[j + 2], a.z + b.z + c.z + d.z);
        atomicAdd(&colsum[j + 3], a.w + b.w + c.w + d.w);
    } else if (wv == 1) {
        float4 a = ssq[0][lane], b = ssq[1][lane], c = ssq[2][lane], d = ssq[3][lane];
        atomicAdd(&colsq[j + 0], a.x + b.x + c.x + d.x);
        atomicAdd(&colsq[j + 1], a.y + b.y + c.y + d.y);
        atomicAdd(&colsq[j + 2], a.z + b.z + c.z + d.z);
        atomicAdd(&colsq[j + 3], a.w + b.w + c.w + d.w);
    }
}

// ---------------- segmented mean pool + fused layer-3 BN/ReLU/residual ----------------
__global__ void k_pool(const unsigned short* __restrict__ hb,
                       const unsigned short* __restrict__ aggb,
                       const int* __restrict__ gstart,
                       const float* __restrict__ colsum, const float* __restrict__ colsq,
                       const float* __restrict__ bng, const float* __restrict__ bnb,
                       float* __restrict__ pooled, float invN) {
    __shared__ float4 sm[4][64];
    int g = blockIdx.x;
    int t = threadIdx.x;
    int lane = t & 63, wv = t >> 6;
    int col = lane * 4;
    float4 cs = *(const float4*)(colsum + col);
    float4 cq = *(const float4*)(colsq + col);
    float4 gg = *(const float4*)(bng + col);
    float4 bb = *(const float4*)(bnb + col);
    float4 scl, shf;
    float mu, var;
    mu = cs.x * invN; var = cq.x * invN - mu * mu; scl.x = gg.x * rsqrtf(var + EPSF); shf.x = bb.x - mu * scl.x;
    mu = cs.y * invN; var = cq.y * invN - mu * mu; scl.y = gg.y * rsqrtf(var + EPSF); shf.y = bb.y - mu * scl.y;
    mu = cs.z * invN; var = cq.z * invN - mu * mu; scl.z = gg.z * rsqrtf(var + EPSF); shf.z = bb.z - mu * scl.z;
    mu = cs.w * invN; var = cq.w * invN - mu * mu; scl.w = gg.w * rsqrtf(var + EPSF); shf.w = bb.w - mu * scl.w;
    int s = gstart[g], e = gstart[g + 1];
    float4 acc = make_float4(0.f, 0.f, 0.f, 0.f);
    for (int n = s + wv; n < e; n += 4) {
        float4 hv = bf4_to_f4(((const ushort4*)(hb + (size_t)n * HH))[lane]);
        float4 av = bf4_to_f4(((const ushort4*)(aggb + (size_t)n * HH))[lane]);
        acc.x += hv.x + fmaxf(av.x * scl.x + shf.x, 0.f);
        acc.y += hv.y + fmaxf(av.y * scl.y + shf.y, 0.f);
        acc.z += hv.z + fmaxf(av.z * scl.z + shf.z, 0.f);
        acc.w += hv.w + fmaxf(av.w * scl.w + shf.w, 0.f);
    }
    sm[wv][lane] = acc;
    __syncthreads();
    if (wv == 0) {
        float4 a = sm[0][lane], b = sm[1][lane], c = sm[2][lane], d = sm[3][lane];
        float inv = 1.0f / fmaxf((float)(e - s), 1.0f);
        float4 r;
        r.x = (a.x + b.x + c.x + d.x) * inv;
        r.y = (a.y + b.y + c.y + d.y) * inv;
        r.z = (a.z + b.z + c.z + d.z) * inv;
        r.w = (a.w + b.w + c.w + d.w) * inv;
        ((float4*)pooled)[(size_t)g * 64 + lane] = r;
    }
}

// ---------------- MLP head: one block per graph ----------------
__global__ void k_head(const float* __restrict__ pooled,
                       const float* __restrict__ W1, const float* __restrict__ b1,
                       const float* __restrict__ W2, const float* __restrict__ b2,
                       float* __restrict__ out) {
    __shared__ float prow[256];
    __shared__ float hred[128];
    int g = blockIdx.x, t = threadIdx.x;  // 128 threads
    prow[t] = pooled[(size_t)g * HH + t];
    prow[t + 128] = pooled[(size_t)g * HH + t + 128];
    __syncthreads();
    float acc = b1[t];
    for (int k = 0; k < HH; ++k) acc += prow[k] * W1[(size_t)k * 128 + t];
    float hid = fmaxf(acc, 0.f);
    hred[t] = hid * W2[t];
    __syncthreads();
    for (int off = 64; off > 0; off >>= 1) {
        if (t < off) hred[t] += hred[t + off];
        __syncthreads();
    }
    if (t == 0) out[g] = hred[0] + b2[0];
}

extern "C" void kernel_launch(void* const* d_in, const int* in_sizes, int n_in,
                              void* d_out, int out_size, void* d_ws, size_t ws_size,
                              hipStream_t stream) {
    const int* x        = (const int*)d_in[0];
    const int* tags     = (const int*)d_in[1];
    const int* ei       = (const int*)d_in[2];
    const int* batch    = (const int*)d_in[3];
    const float* atom_e = (const float*)d_in[4];
    const float* tag_e  = (const float*)d_in[5];
    const float* Wp     = (const float*)d_in[6];
    const float* bp     = (const float*)d_in[7];
    const float* gcn_W  = (const float*)d_in[8];
    const float* gcn_b  = (const float*)d_in[9];
    const float* bn_g   = (const float*)d_in[10];
    const float* bn_b   = (const float*)d_in[11];
    const float* W1     = (const float*)d_in[12];
    const float* b1     = (const float*)d_in[13];
    const float* W2     = (const float*)d_in[14];
    const float* b2     = (const float*)d_in[15];
    float* out = (float*)d_out;

    const int N = NN, E = EE, G = GG, H = HH;
    const int Mpad = ((N + 127) / 128) * 128;  // 50048
    const float invN = 1.0f / (float)N;

    char* p = (char*)d_ws;
    auto alloc = [&](size_t bytes) {
        void* r = (void*)p;
        p += (bytes + 255) & ~(size_t)255;
        return r;
    };
    unsigned short* hbA = (unsigned short*)alloc((size_t)Mpad * H * 2);
    unsigned short* hbB = (unsigned short*)alloc((size_t)Mpad * H * 2);
    unsigned short* hwb = (unsigned short*)alloc((size_t)Mpad * H * 2);
    unsigned short* Wt  = (unsigned short*)alloc((size_t)LL * H * H * 2);
    unsigned short* aggb= (unsigned short*)alloc((size_t)N * H * 2);
    float* dinv = (float*)alloc((size_t)N * 4);
    int* rs     = (int*)alloc((size_t)N * 4);
    int* csr    = (int*)alloc((size_t)E * 4);
    int* bsum   = (int*)alloc(64 * 4);
    float* aref = (float*)alloc(100 * (size_t)H * 4);
    float* tref = (float*)alloc(3 * (size_t)H * 4);
    int* gstart = (int*)alloc((size_t)(G + 1) * 4);
    float* pooled = (float*)alloc((size_t)G * H * 4);
    // zero-init region: cnt | cur | cstat[4][512] (contiguous allocs, one memset)
    int* cnt    = (int*)alloc((size_t)N * 4);
    int* cur    = (int*)alloc((size_t)N * 4);
    float* cstat= (float*)alloc((size_t)LL * 512 * 4);
    size_t zspan = (size_t)((char*)cstat + (size_t)LL * 512 * 4 - (char*)cnt);

    const int* src = ei;
    const int* dst = ei + E;

    hipMemsetAsync(cnt, 0, zspan, stream);

    k_degree<<<(E + 255) / 256, 256, 0, stream>>>(dst, cnt, E);
    int nb = (N + 1023) / 1024;
    k_scan1<<<nb, 1024, 0, stream>>>(cnt, rs, bsum, N);
    k_scan2<<<1, 64, 0, stream>>>(bsum, nb);
    k_scan3<<<(N + 255) / 256, 256, 0, stream>>>(rs, cnt, bsum, dinv, N);
    k_scatter<<<(E + 255) / 256, 256, 0, stream>>>(src, dst, rs, cur, csr, E);
    k_gbound<<<(N + 255) / 256, 256, 0, stream>>>(batch, gstart, N, G);
    k_projw<<<359, 256, 0, stream>>>(atom_e, tag_e, Wp, bp, gcn_W, aref, tref, Wt);

    // ping-pong residual state: layer0 writes hbA; 1->hbB; 2->hbA; 3->hbB
    unsigned short* hbw[4] = {hbA, hbB, hbA, hbB};
    for (int l = 0; l < LL; ++l) {
        const unsigned short* hr = (l == 0) ? hbA : hbw[l - 1];
        const float* cprev = cstat + (size_t)(l > 0 ? l - 1 : 0) * 512;
        const float* bngp = bn_g + (size_t)(l > 0 ? l - 1 : 0) * H;
        const float* bnbp = bn_b + (size_t)(l > 0 ? l - 1 : 0) * H;
        k_gemm<<<dim3(2, Mpad / 128), 256, 0, stream>>>(
            hr, Wt + (size_t)l * H * H, dinv, hwb,
            (l == 0) ? 0 : 1, x, tags, aref, tref, aggb,
            cprev, cprev + 256, bngp, bnbp, hbw[l], N, invN);
        k_agg<<<(N + 3) / 4, 256, 0, stream>>>(hwb, aggb, csr, rs, cnt, dinv,
                                               gcn_b + (size_t)l * H, N);
        k_bnstats<<<512, 256, 0, stream>>>((const ushort4*)aggb,
                                           cstat + (size_t)l * 512,
                                           cstat + (size_t)l * 512 + 256, N);
    }

    k_pool<<<G, 256, 0, stream>>>(hbw[3], aggb, gstart,
                                  cstat + 3 * 512, cstat + 3 * 512 + 256,
                                  bn_g + 3 * (size_t)H, bn_b + 3 * (size_t)H,
                                  pooled, invN);
    k_head<<<G, 128, 0, stream>>>(pooled, W1, b1, W2, b2, out);
}

// Round 8
// 819.801 us; speedup vs baseline: 1.5909x; 1.0574x over previous
//
#include <hip/hip_runtime.h>
#include <hip/hip_bf16.h>

#define NN 50000
#define EE 800000
#define GG 512
#define HH 256
#define TT 32
#define LL 4
#define EPSF 1e-5f

typedef __attribute__((ext_vector_type(8))) short short8;
typedef __attribute__((ext_vector_type(4))) float float4v;

// ---------- bf16 helpers ----------
__device__ inline unsigned short f2b(float f) {  // RNE
    unsigned u = __float_as_uint(f);
    unsigned r = (u + 0x7FFFu + ((u >> 16) & 1u)) >> 16;
    return (unsigned short)r;
}
__device__ inline unsigned pack2(float lo, float hi) {  // v_cvt_pk_bf16_f32
    __hip_bfloat162 b2 = __float22bfloat162_rn(float2{lo, hi});
    return *reinterpret_cast<unsigned*>(&b2);
}
__device__ inline float4 bf4_to_f4(ushort4 u) {
    float4 f;
    f.x = __uint_as_float((unsigned)u.x << 16);
    f.y = __uint_as_float((unsigned)u.y << 16);
    f.z = __uint_as_float((unsigned)u.z << 16);
    f.w = __uint_as_float((unsigned)u.w << 16);
    return f;
}

// ---------------- degree ----------------
__global__ void k_degree(const int* __restrict__ dst, int* __restrict__ cnt, int E) {
    int e = blockIdx.x * 256 + threadIdx.x;
    if (e < E) atomicAdd(&cnt[dst[e]], 1);
}

// ---------------- scan (3-phase) ----------------
__global__ void k_scan1(const int* __restrict__ cnt, int* __restrict__ incl,
                        int* __restrict__ bsum, int N) {
    __shared__ int s[1024];
    int i = blockIdx.x * 1024 + threadIdx.x;
    int v = (i < N) ? cnt[i] : 0;
    s[threadIdx.x] = v;
    __syncthreads();
    for (int off = 1; off < 1024; off <<= 1) {
        int t = (threadIdx.x >= off) ? s[threadIdx.x - off] : 0;
        __syncthreads();
        s[threadIdx.x] += t;
        __syncthreads();
    }
    if (i < N) incl[i] = s[threadIdx.x];
    if (threadIdx.x == 1023) bsum[blockIdx.x] = s[1023];
}

__global__ void k_scan2(int* __restrict__ bsum, int nb) {
    __shared__ int s[64];
    int v = (threadIdx.x < nb) ? bsum[threadIdx.x] : 0;
    s[threadIdx.x] = v;
    __syncthreads();
    for (int off = 1; off < 64; off <<= 1) {
        int t = (threadIdx.x >= off) ? s[threadIdx.x - off] : 0;
        __syncthreads();
        s[threadIdx.x] += t;
        __syncthreads();
    }
    if (threadIdx.x < nb) bsum[threadIdx.x] = s[threadIdx.x] - v;  // exclusive
}

// scan3 + dinv fused
__global__ void k_scan3(int* __restrict__ rs, const int* __restrict__ cnt,
                        const int* __restrict__ boff, float* __restrict__ dinv, int N) {
    int i = blockIdx.x * 256 + threadIdx.x;
    if (i < N) {
        int c = cnt[i];
        rs[i] = rs[i] + boff[i >> 10] - c;  // exclusive prefix
        dinv[i] = rsqrtf((float)c + 1.0f);
    }
}

__global__ void k_scatter(const int* __restrict__ src, const int* __restrict__ dst,
                          const int* __restrict__ rs, int* __restrict__ cur,
                          int* __restrict__ csr, int E) {
    int e = blockIdx.x * 256 + threadIdx.x;
    if (e >= E) return;
    int d = dst[e];
    int p = rs[d] + atomicAdd(&cur[d], 1);
    csr[p] = src[e];
}

// ---------------- graph boundaries (batch sorted), tail handled inline ----------------
__global__ void k_gbound(const int* __restrict__ batch, int* __restrict__ gstart,
                         int N, int G) {
    int n = blockIdx.x * 256 + threadIdx.x;
    if (n >= N) return;
    int b = batch[n];
    int prev = (n == 0) ? -1 : batch[n - 1];
    for (int g = prev + 1; g <= b; ++g) gstart[g] = n;
    if (n == N - 1)
        for (int g = b + 1; g <= G; ++g) gstart[g] = N;
}

// ---------------- fused proj (atom/tag tables) + weight transpose ----------------
__global__ void k_projw(const float* __restrict__ atom_emb, const float* __restrict__ tag_emb,
                        const float* __restrict__ Wp, const float* __restrict__ bp,
                        const float* __restrict__ W,
                        float* __restrict__ aref, float* __restrict__ tref,
                        unsigned short* __restrict__ Wt) {
    int blk = blockIdx.x;
    if (blk < 256) {  // wprep: Wt[l][n][k] bf16
        int l = blk >> 6;
        int bx = blk & 63;
        int n = bx * 4 + (threadIdx.x >> 6);
        int kq = (threadIdx.x & 63) * 4;
        const float* Wl = W + (size_t)l * HH * HH;
        ushort4 o;
        o.x = f2b(Wl[(size_t)(kq + 0) * HH + n]);
        o.y = f2b(Wl[(size_t)(kq + 1) * HH + n]);
        o.z = f2b(Wl[(size_t)(kq + 2) * HH + n]);
        o.w = f2b(Wl[(size_t)(kq + 3) * HH + n]);
        *(ushort4*)(Wt + (size_t)l * HH * HH + (size_t)n * HH + kq) = o;
    } else {
        int r = blk - 256;  // 0..102
        int j = threadIdx.x;
        if (r < 100) {
            float acc = bp[j];
            for (int k = 0; k < HH; ++k) acc += atom_emb[r * HH + k] * Wp[(size_t)k * HH + j];
            aref[r * HH + j] = acc;
        } else {
            int tr = r - 100;
            float acc = 0.f;
            for (int k = 0; k < TT; ++k) acc += tag_emb[tr * TT + k] * Wp[(size_t)(HH + k) * HH + j];
            tref[tr * HH + j] = acc;
        }
    }
}

// ---------------- fused MFMA GEMM, 128x256 tile, single A pass ----------------
// hwb[M,256] = bf16( (A @ Wt^T) * dinv[row] )
// mode 0 (layer 0): A[row] = aref[x[row]] + tref[tags[row]]        (h0 fused)
// mode 1 (layers 1+): A[row] = hb_read[row] + relu(bn(aggb[row]))  (epi fused)
// Each block covers all 256 output cols, so A is computed once and written to hb_out.
__global__ __launch_bounds__(512, 2) void k_gemm(
    const unsigned short* __restrict__ hb_read,
    const unsigned short* __restrict__ Wt,
    const float* __restrict__ dinv,
    unsigned short* __restrict__ hwb,
    int mode,
    const int* __restrict__ x, const int* __restrict__ tags,
    const float* __restrict__ aref, const float* __restrict__ tref,
    const unsigned short* __restrict__ aggb,
    const float* __restrict__ colsum, const float* __restrict__ colsq,
    const float* __restrict__ bng, const float* __restrict__ bnb,
    unsigned short* __restrict__ hb_out,
    int M, float invN) {
    __shared__ unsigned short As[128][72];
    __shared__ unsigned short Bs[256][72];
    __shared__ float sc[256], sh[256];
    int t = threadIdx.x;              // 0..511
    int lane = t & 63, w = t >> 6;    // 8 waves
    int wr = w & 1, wc = w >> 1;      // wave covers rows [wr*64,+64), cols [wc*64,+64)
    int l15 = lane & 15, l4 = lane >> 4;
    int row0 = blockIdx.x * 128;

    if (mode == 1 && t < 256) {  // per-column BN scale/shift
        float mu = colsum[t] * invN;
        float var = colsq[t] * invN - mu * mu;
        float s = bng[t] * rsqrtf(var + EPSF);
        sc[t] = s;
        sh[t] = bnb[t] - mu * s;
    }
    __syncthreads();

    float4v acc[4][4];
#pragma unroll
    for (int i = 0; i < 4; ++i)
#pragma unroll
        for (int j = 0; j < 4; ++j) acc[i][j] = (float4v)0.f;

    for (int k0 = 0; k0 < 256; k0 += 64) {
        if (k0) __syncthreads();
        // B tile: 256 n-rows x 64 k
#pragma unroll
        for (int u = 0; u < 4; ++u) {
            int idx = u * 512 + t;          // 0..2047
            int rb = idx >> 3;              // 0..255
            int c = (idx & 7) * 8;
            *(uint4*)&Bs[rb][c] = *(const uint4*)(Wt + (size_t)rb * 256 + k0 + c);
        }
        // A tile: 128 rows x 64 k (computed once per row-block)
#pragma unroll
        for (int u = 0; u < 2; ++u) {
            int idx = u * 512 + t;          // 0..1023
            int r = idx >> 3;               // 0..127
            int c = (idx & 7) * 8;
            int grow = row0 + r;
            int gcol = k0 + c;
            uint4 ov;
            if (grow < M) {
                unsigned o[4];
                if (mode == 0) {
                    const float* ar = aref + (size_t)x[grow] * 256 + gcol;
                    const float* tr = tref + (size_t)tags[grow] * 256 + gcol;
                    float4 a0 = *(const float4*)ar, a1 = *(const float4*)(ar + 4);
                    float4 t0 = *(const float4*)tr, t1 = *(const float4*)(tr + 4);
                    o[0] = pack2(a0.x + t0.x, a0.y + t0.y);
                    o[1] = pack2(a0.z + t0.z, a0.w + t0.w);
                    o[2] = pack2(a1.x + t1.x, a1.y + t1.y);
                    o[3] = pack2(a1.z + t1.z, a1.w + t1.w);
                } else {
                    uint4 hv = *(const uint4*)(hb_read + (size_t)grow * 256 + gcol);
                    uint4 av = *(const uint4*)(aggb + (size_t)grow * 256 + gcol);
                    const unsigned* hvp = (const unsigned*)&hv;
                    const unsigned* avp = (const unsigned*)&av;
#pragma unroll
                    for (int j = 0; j < 4; ++j) {
                        unsigned hj = hvp[j], aj = avp[j];
                        float h0 = __uint_as_float(hj << 16);
                        float h1 = __uint_as_float(hj & 0xFFFF0000u);
                        float a0 = __uint_as_float(aj << 16);
                        float a1 = __uint_as_float(aj & 0xFFFF0000u);
                        int cc = gcol + j * 2;
                        float v0 = fmaxf(a0 * sc[cc] + sh[cc], 0.f);
                        float v1 = fmaxf(a1 * sc[cc + 1] + sh[cc + 1], 0.f);
                        o[j] = pack2(h0 + v0, h1 + v1);
                    }
                }
                ov = make_uint4(o[0], o[1], o[2], o[3]);
                *(uint4*)(hb_out + (size_t)grow * 256 + gcol) = ov;
            } else {
                ov = make_uint4(0u, 0u, 0u, 0u);
            }
            *(uint4*)&As[r][c] = ov;
        }
        __syncthreads();
#pragma unroll
        for (int kk = 0; kk < 64; kk += 32) {
            short8 a[4], b[4];
#pragma unroll
            for (int i = 0; i < 4; ++i)
                a[i] = *(const short8*)&As[wr * 64 + i * 16 + l15][kk + l4 * 8];
#pragma unroll
            for (int i = 0; i < 4; ++i)
                b[i] = *(const short8*)&Bs[wc * 64 + i * 16 + l15][kk + l4 * 8];
#pragma unroll
            for (int mi = 0; mi < 4; ++mi)
#pragma unroll
                for (int ni = 0; ni < 4; ++ni)
                    acc[mi][ni] = __builtin_amdgcn_mfma_f32_16x16x32_bf16(
                        a[mi], b[ni], acc[mi][ni], 0, 0, 0);
        }
    }
    // epilogue: C/D layout col=lane&15, row=(lane>>4)*4+reg
#pragma unroll
    for (int mi = 0; mi < 4; ++mi) {
        int mb = row0 + wr * 64 + mi * 16 + l4 * 4;
        float dv[4];
#pragma unroll
        for (int r = 0; r < 4; ++r) dv[r] = (mb + r < M) ? dinv[mb + r] : 0.f;
#pragma unroll
        for (int ni = 0; ni < 4; ++ni) {
            int n = wc * 64 + ni * 16 + l15;
#pragma unroll
            for (int r = 0; r < 4; ++r) {
                if (mb + r < M)
                    hwb[(size_t)(mb + r) * 256 + n] = f2b(acc[mi][ni][r] * dv[r]);
            }
        }
    }
}

// ---------------- CSR aggregation (bf16 row gathers, 8x unrolled): one wave/node ----------------
__global__ void k_agg(const unsigned short* __restrict__ hwb, unsigned short* __restrict__ aggb,
                      const int* __restrict__ csr, const int* __restrict__ rs,
                      const int* __restrict__ cnt, const float* __restrict__ dinv,
                      const float* __restrict__ bias, int N) {
    int wave = threadIdx.x >> 6;
    int lane = threadIdx.x & 63;
    int n = blockIdx.x * 4 + wave;
    if (n >= N) return;
    float dn = dinv[n];
    int e = rs[n];
    int end = e + cnt[n];
    // self term (hwb already carries dinv[src])
    float4 acc = bf4_to_f4(((const ushort4*)(hwb + (size_t)n * HH))[lane]);
    for (; e + 8 <= end; e += 8) {
        int s0 = csr[e],     s1 = csr[e + 1], s2 = csr[e + 2], s3 = csr[e + 3];
        int s4 = csr[e + 4], s5 = csr[e + 5], s6 = csr[e + 6], s7 = csr[e + 7];
        float4 m0 = bf4_to_f4(((const ushort4*)(hwb + (size_t)s0 * HH))[lane]);
        float4 m1 = bf4_to_f4(((const ushort4*)(hwb + (size_t)s1 * HH))[lane]);
        float4 m2 = bf4_to_f4(((const ushort4*)(hwb + (size_t)s2 * HH))[lane]);
        float4 m3 = bf4_to_f4(((const ushort4*)(hwb + (size_t)s3 * HH))[lane]);
        float4 m4 = bf4_to_f4(((const ushort4*)(hwb + (size_t)s4 * HH))[lane]);
        float4 m5 = bf4_to_f4(((const ushort4*)(hwb + (size_t)s5 * HH))[lane]);
        float4 m6 = bf4_to_f4(((const ushort4*)(hwb + (size_t)s6 * HH))[lane]);
        float4 m7 = bf4_to_f4(((const ushort4*)(hwb + (size_t)s7 * HH))[lane]);
        acc.x += ((m0.x + m1.x) + (m2.x + m3.x)) + ((m4.x + m5.x) + (m6.x + m7.x));
        acc.y += ((m0.y + m1.y) + (m2.y + m3.y)) + ((m4.y + m5.y) + (m6.y + m7.y));
        acc.z += ((m0.z + m1.z) + (m2.z + m3.z)) + ((m4.z + m5.z) + (m6.z + m7.z));
        acc.w += ((m0.w + m1.w) + (m2.w + m3.w)) + ((m4.w + m5.w) + (m6.w + m7.w));
    }
    for (; e + 4 <= end; e += 4) {
        int s0 = csr[e], s1 = csr[e + 1], s2 = csr[e + 2], s3 = csr[e + 3];
        float4 m0 = bf4_to_f4(((const ushort4*)(hwb + (size_t)s0 * HH))[lane]);
        float4 m1 = bf4_to_f4(((const ushort4*)(hwb + (size_t)s1 * HH))[lane]);
        float4 m2 = bf4_to_f4(((const ushort4*)(hwb + (size_t)s2 * HH))[lane]);
        float4 m3 = bf4_to_f4(((const ushort4*)(hwb + (size_t)s3 * HH))[lane]);
        acc.x += (m0.x + m1.x) + (m2.x + m3.x);
        acc.y += (m0.y + m1.y) + (m2.y + m3.y);
        acc.z += (m0.z + m1.z) + (m2.z + m3.z);
        acc.w += (m0.w + m1.w) + (m2.w + m3.w);
    }
    for (; e < end; ++e) {
        int s = csr[e];
        float4 m = bf4_to_f4(((const ushort4*)(hwb + (size_t)s * HH))[lane]);
        acc.x += m.x; acc.y += m.y; acc.z += m.z; acc.w += m.w;
    }
    float4 b = ((const float4*)bias)[lane];
    ushort4 u;
    u.x = f2b(acc.x * dn + b.x); u.y = f2b(acc.y * dn + b.y);
    u.z = f2b(acc.z * dn + b.z); u.w = f2b(acc.w * dn + b.w);
    ((ushort4*)(aggb + (size_t)n * HH))[lane] = u;
}

// ---------------- BN stats (col sum / sumsq) over bf16 agg ----------------
__global__ __launch_bounds__(256) void k_bnstats(const ushort4* __restrict__ aggb,
                                                 float* __restrict__ colsum,
                                                 float* __restrict__ colsq, int N) {
    __shared__ float4 ssum[4][64];
    __shared__ float4 ssq[4][64];
    int lane = threadIdx.x & 63;
    int wv = threadIdx.x >> 6;
    int rows_per = (N + gridDim.x - 1) / gridDim.x;
    int r0 = blockIdx.x * rows_per;
    int r1 = r0 + rows_per; if (r1 > N) r1 = N;
    float4 s = make_float4(0.f, 0.f, 0.f, 0.f);
    float4 s2 = make_float4(0.f, 0.f, 0.f, 0.f);
    for (int r = r0 + wv; r < r1; r += 4) {
        float4 v = bf4_to_f4(aggb[(size_t)r * 64 + lane]);
        s.x += v.x; s.y += v.y; s.z += v.z; s.w += v.w;
        s2.x += v.x * v.x; s2.y += v.y * v.y; s2.z += v.z * v.z; s2.w += v.w * v.w;
    }
    ssum[wv][lane] = s;
    ssq[wv][lane] = s2;
    __syncthreads();
    int j = lane * 4;
    if (wv == 0) {
        float4 a = ssum[0][lane], b = ssum[1][lane], c = ssum[2][lane], d = ssum[3][lane];
        atomicAdd(&colsum[j + 0], a.x + b.x + c.x + d.x);
        atomicAdd(&colsum[j + 1], a.y + b.y + c.y + d.y);
        atomicAdd(&colsum[j + 2], a.z + b.z + c.z + d.z);
        atomicAdd(&colsum[j + 3], a.w + b.w + c.w + d.w);
    } else if (wv == 1) {
        float4 a = ssq[0][lane], b = ssq[1][lane], c = ssq[2][lane], d = ssq[3][lane];
        atomicAdd(&colsq[j + 0], a.x + b.x + c.x + d.x);
        atomicAdd(&colsq[j + 1], a.y + b.y + c.y + d.y);
        atomicAdd(&colsq[j + 2], a.z + b.z + c.z + d.z);
        atomicAdd(&colsq[j + 3], a.w + b.w + c.w + d.w);
    }
}

// ---------------- segmented mean pool + fused layer-3 BN/ReLU/residual ----------------
__global__ void k_pool(const unsigned short* __restrict__ hb,
                       const unsigned short* __restrict__ aggb,
                       const int* __restrict__ gstart,
                       const float* __restrict__ colsum, const float* __restrict__ colsq,
                       const float* __restrict__ bng, const float* __restrict__ bnb,
                       float* __restrict__ pooled, float invN) {
    __shared__ float4 sm[4][64];
    int g = blockIdx.x;
    int t = threadIdx.x;
    int lane = t & 63, wv = t >> 6;
    int col = lane * 4;
    float4 cs = *(const float4*)(colsum + col);
    float4 cq = *(const float4*)(colsq + col);
    float4 gg = *(const float4*)(bng + col);
    float4 bb = *(const float4*)(bnb + col);
    float4 scl, shf;
    float mu, var;
    mu = cs.x * invN; var = cq.x * invN - mu * mu; scl.x = gg.x * rsqrtf(var + EPSF); shf.x = bb.x - mu * scl.x;
    mu = cs.y * invN; var = cq.y * invN - mu * mu; scl.y = gg.y * rsqrtf(var + EPSF); shf.y = bb.y - mu * scl.y;
    mu = cs.z * invN; var = cq.z * invN - mu * mu; scl.z = gg.z * rsqrtf(var + EPSF); shf.z = bb.z - mu * scl.z;
    mu = cs.w * invN; var = cq.w * invN - mu * mu; scl.w = gg.w * rsqrtf(var + EPSF); shf.w = bb.w - mu * scl.w;
    int s = gstart[g], e = gstart[g + 1];
    float4 acc = make_float4(0.f, 0.f, 0.f, 0.f);
    for (int n = s + wv; n < e; n += 4) {
        float4 hv = bf4_to_f4(((const ushort4*)(hb + (size_t)n * HH))[lane]);
        float4 av = bf4_to_f4(((const ushort4*)(aggb + (size_t)n * HH))[lane]);
        acc.x += hv.x + fmaxf(av.x * scl.x + shf.x, 0.f);
        acc.y += hv.y + fmaxf(av.y * scl.y + shf.y, 0.f);
        acc.z += hv.z + fmaxf(av.z * scl.z + shf.z, 0.f);
        acc.w += hv.w + fmaxf(av.w * scl.w + shf.w, 0.f);
    }
    sm[wv][lane] = acc;
    __syncthreads();
    if (wv == 0) {
        float4 a = sm[0][lane], b = sm[1][lane], c = sm[2][lane], d = sm[3][lane];
        float inv = 1.0f / fmaxf((float)(e - s), 1.0f);
        float4 r;
        r.x = (a.x + b.x + c.x + d.x) * inv;
        r.y = (a.y + b.y + c.y + d.y) * inv;
        r.z = (a.z + b.z + c.z + d.z) * inv;
        r.w = (a.w + b.w + c.w + d.w) * inv;
        ((float4*)pooled)[(size_t)g * 64 + lane] = r;
    }
}

// ---------------- MLP head: one block per graph ----------------
__global__ void k_head(const float* __restrict__ pooled,
                       const float* __restrict__ W1, const float* __restrict__ b1,
                       const float* __restrict__ W2, const float* __restrict__ b2,
                       float* __restrict__ out) {
    __shared__ float prow[256];
    __shared__ float hred[128];
    int g = blockIdx.x, t = threadIdx.x;  // 128 threads
    prow[t] = pooled[(size_t)g * HH + t];
    prow[t + 128] = pooled[(size_t)g * HH + t + 128];
    __syncthreads();
    float acc = b1[t];
    for (int k = 0; k < HH; ++k) acc += prow[k] * W1[(size_t)k * 128 + t];
    float hid = fmaxf(acc, 0.f);
    hred[t] = hid * W2[t];
    __syncthreads();
    for (int off = 64; off > 0; off >>= 1) {
        if (t < off) hred[t] += hred[t + off];
        __syncthreads();
    }
    if (t == 0) out[g] = hred[0] + b2[0];
}

extern "C" void kernel_launch(void* const* d_in, const int* in_sizes, int n_in,
                              void* d_out, int out_size, void* d_ws, size_t ws_size,
                              hipStream_t stream) {
    const int* x        = (const int*)d_in[0];
    const int* tags     = (const int*)d_in[1];
    const int* ei       = (const int*)d_in[2];
    const int* batch    = (const int*)d_in[3];
    const float* atom_e = (const float*)d_in[4];
    const float* tag_e  = (const float*)d_in[5];
    const float* Wp     = (const float*)d_in[6];
    const float* bp     = (const float*)d_in[7];
    const float* gcn_W  = (const float*)d_in[8];
    const float* gcn_b  = (const float*)d_in[9];
    const float* bn_g   = (const float*)d_in[10];
    const float* bn_b   = (const float*)d_in[11];
    const float* W1     = (const float*)d_in[12];
    const float* b1     = (const float*)d_in[13];
    const float* W2     = (const float*)d_in[14];
    const float* b2     = (const float*)d_in[15];
    float* out = (float*)d_out;

    const int N = NN, E = EE, G = GG, H = HH;
    const int Mpad = ((N + 127) / 128) * 128;  // 50048
    const float invN = 1.0f / (float)N;

    char* p = (char*)d_ws;
    auto alloc = [&](size_t bytes) {
        void* r = (void*)p;
        p += (bytes + 255) & ~(size_t)255;
        return r;
    };
    unsigned short* hbA = (unsigned short*)alloc((size_t)Mpad * H * 2);
    unsigned short* hbB = (unsigned short*)alloc((size_t)Mpad * H * 2);
    unsigned short* hwb = (unsigned short*)alloc((size_t)Mpad * H * 2);
    unsigned short* Wt  = (unsigned short*)alloc((size_t)LL * H * H * 2);
    unsigned short* aggb= (unsigned short*)alloc((size_t)N * H * 2);
    float* dinv = (float*)alloc((size_t)N * 4);
    int* rs     = (int*)alloc((size_t)N * 4);
    int* csr    = (int*)alloc((size_t)E * 4);
    int* bsum   = (int*)alloc(64 * 4);
    float* aref = (float*)alloc(100 * (size_t)H * 4);
    float* tref = (float*)alloc(3 * (size_t)H * 4);
    int* gstart = (int*)alloc((size_t)(G + 1) * 4);
    float* pooled = (float*)alloc((size_t)G * H * 4);
    // zero-init region: cnt | cur | cstat[4][512] (contiguous allocs, one memset)
    int* cnt    = (int*)alloc((size_t)N * 4);
    int* cur    = (int*)alloc((size_t)N * 4);
    float* cstat= (float*)alloc((size_t)LL * 512 * 4);
    size_t zspan = (size_t)((char*)cstat + (size_t)LL * 512 * 4 - (char*)cnt);

    const int* src = ei;
    const int* dst = ei + E;

    hipMemsetAsync(cnt, 0, zspan, stream);

    k_degree<<<(E + 255) / 256, 256, 0, stream>>>(dst, cnt, E);
    int nb = (N + 1023) / 1024;
    k_scan1<<<nb, 1024, 0, stream>>>(cnt, rs, bsum, N);
    k_scan2<<<1, 64, 0, stream>>>(bsum, nb);
    k_scan3<<<(N + 255) / 256, 256, 0, stream>>>(rs, cnt, bsum, dinv, N);
    k_scatter<<<(E + 255) / 256, 256, 0, stream>>>(src, dst, rs, cur, csr, E);
    k_gbound<<<(N + 255) / 256, 256, 0, stream>>>(batch, gstart, N, G);
    k_projw<<<359, 256, 0, stream>>>(atom_e, tag_e, Wp, bp, gcn_W, aref, tref, Wt);

    // ping-pong residual state: layer0 writes hbA; 1->hbB; 2->hbA; 3->hbB
    unsigned short* hbw[4] = {hbA, hbB, hbA, hbB};
    for (int l = 0; l < LL; ++l) {
        const unsigned short* hr = (l == 0) ? hbA : hbw[l - 1];
        const float* cprev = cstat + (size_t)(l > 0 ? l - 1 : 0) * 512;
        const float* bngp = bn_g + (size_t)(l > 0 ? l - 1 : 0) * H;
        const float* bnbp = bn_b + (size_t)(l > 0 ? l - 1 : 0) * H;
        k_gemm<<<dim3(Mpad / 128), 512, 0, stream>>>(
            hr, Wt + (size_t)l * H * H, dinv, hwb,
            (l == 0) ? 0 : 1, x, tags, aref, tref, aggb,
            cprev, cprev + 256, bngp, bnbp, hbw[l], N, invN);
        k_agg<<<(N + 3) / 4, 256, 0, stream>>>(hwb, aggb, csr, rs, cnt, dinv,
                                               gcn_b + (size_t)l * H, N);
        k_bnstats<<<512, 256, 0, stream>>>((const ushort4*)aggb,
                                           cstat + (size_t)l * 512,
                                           cstat + (size_t)l * 512 + 256, N);
    }

    k_pool<<<G, 256, 0, stream>>>(hbw[3], aggb, gstart,
                                  cstat + 3 * 512, cstat + 3 * 512 + 256,
                                  bn_g + 3 * (size_t)H, bn_b + 3 * (size_t)H,
                                  pooled, invN);
    k_head<<<G, 128, 0, stream>>>(pooled, W1, b1, W2, b2, out);
}